// Round 6
// baseline (225.893 us; speedup 1.0000x reference)
//
#include <hip/hip_runtime.h>

typedef __bf16 bf16_t;
typedef bf16_t bf16x4 __attribute__((ext_vector_type(4)));
typedef bf16_t bf16x8 __attribute__((ext_vector_type(8)));
typedef float f32x4 __attribute__((ext_vector_type(4)));

#define B_ 4
#define T_ 2048
#define C_ 1024
#define H_ 16
#define D_ 64

// global -> LDS direct copy, 16B per lane; LDS dest must be wave-uniform base
// (HW adds lane*16). Source is per-lane (pre-swizzled to realize LDS swizzle).
#define GLDS(g, l)                                                          \
  __builtin_amdgcn_global_load_lds(                                         \
      (const __attribute__((address_space(1))) void*)(g),                   \
      (__attribute__((address_space(3))) void*)(l), 16, 0, 0)

static __device__ __forceinline__ f32x4 mfma16(bf16x8 a, bf16x8 b, f32x4 c) {
  return __builtin_amdgcn_mfma_f32_16x16x32_bf16(a, b, c, 0, 0, 0);
}

// ---------------------------------------------------------------- convert
// One launch converts x + the 4 weight matrices.
__global__ void cvt_all(const float* __restrict__ x, const float* __restrict__ wq,
                        const float* __restrict__ wk, const float* __restrict__ wv,
                        const float* __restrict__ wp, bf16_t* __restrict__ xb,
                        bf16_t* __restrict__ wqb, bf16_t* __restrict__ wkb,
                        bf16_t* __restrict__ wvb, bf16_t* __restrict__ wpb) {
  int i = blockIdx.x * blockDim.x + threadIdx.x;  // float4 index
  const float* src;
  bf16_t* dst;
  int off;
  if (i < 2097152) {
    src = x; dst = xb; off = i;
  } else {
    int r = i - 2097152;
    int region = r >> 18;  // 262144 float4 per weight
    off = r & 262143;
    if (region == 0) { src = wq; dst = wqb; }
    else if (region == 1) { src = wk; dst = wkb; }
    else if (region == 2) { src = wv; dst = wvb; }
    else { src = wp; dst = wpb; }
  }
  float4 v = ((const float4*)src)[off];
  bf16x4 o = {(bf16_t)v.x, (bf16_t)v.y, (bf16_t)v.z, (bf16_t)v.w};
  ((bf16x4*)dst)[off] = o;
}

// ------------------------------------------------------------ GEMM main loop
// C = A(MxK) * W(NxK)^T, 128x128 tile, BK=64, 256 threads = 2x2 waves,
// each wave 64x64 = 4x4 fragments of 16x16x32 bf16 MFMA.
// LDS tiles [128 rows][64 bf16] (128B rows), XOR-swizzled 16B chunks:
// phys_chunk = chunk ^ (row & 7). Staged linearly via global_load_lds with
// inverse-swizzled global source (same involution).
__device__ __forceinline__ void gemm_mainloop(const bf16_t* __restrict__ A,
                                              const bf16_t* __restrict__ W,
                                              bf16_t* lA, bf16_t* lB, int row0,
                                              int col0, f32x4 (&acc)[4][4]) {
  const int tid = threadIdx.x;
  const int wave = tid >> 6, lane = tid & 63;
  const int wr = wave >> 1, wc = wave & 1;
  for (int k0 = 0; k0 < C_; k0 += 64) {
#pragma unroll
    for (int it = 0; it < 4; ++it) {
      const int off = (it * 4 + wave) * 1024;  // bytes, wave-uniform
      const int lin = off + lane * 16;
      const int r = lin >> 7;
      const int c = ((lin >> 4) & 7) ^ (r & 7);
      GLDS(A + (size_t)(row0 + r) * C_ + k0 + c * 8, lA + (off >> 1));
      GLDS(W + (size_t)(col0 + r) * C_ + k0 + c * 8, lB + (off >> 1));
    }
    __syncthreads();
#pragma unroll
    for (int s = 0; s < 2; ++s) {
      bf16x8 af[4], bfr[4];
#pragma unroll
      for (int m = 0; m < 4; ++m) {
        const int r = wr * 64 + m * 16 + (lane & 15);
        const int c = s * 4 + (lane >> 4);
        af[m] = *(const bf16x8*)((const char*)lA + r * 128 +
                                 ((c ^ (r & 7)) << 4));
      }
#pragma unroll
      for (int n = 0; n < 4; ++n) {
        const int r = wc * 64 + n * 16 + (lane & 15);
        const int c = s * 4 + (lane >> 4);
        bfr[n] = *(const bf16x8*)((const char*)lB + r * 128 +
                                  ((c ^ (r & 7)) << 4));
      }
#pragma unroll
      for (int m = 0; m < 4; ++m)
#pragma unroll
        for (int n = 0; n < 4; ++n) acc[m][n] = mfma16(af[m], bfr[n], acc[m][n]);
    }
    __syncthreads();
  }
}

// QKV projection. z=0: Q (pre-scaled by log2(e)/sqrt(D)) -> [B][H][T][D];
// z=1: K -> [B][H][T][D]; z=2: V -> transposed [B][H][D][T].
__global__ __launch_bounds__(256) void gemm_qkv(
    const bf16_t* __restrict__ xb, const bf16_t* __restrict__ wq,
    const bf16_t* __restrict__ wk, const bf16_t* __restrict__ wv,
    bf16_t* __restrict__ qo, bf16_t* __restrict__ ko, bf16_t* __restrict__ vt) {
  __shared__ bf16_t lA[128 * 64];
  __shared__ bf16_t lB[128 * 64];
  const int z = blockIdx.z;
  const bf16_t* W = (z == 0) ? wq : ((z == 1) ? wk : wv);
  bf16_t* outb = (z == 0) ? qo : ((z == 1) ? ko : vt);
  const int row0 = blockIdx.y * 128, col0 = blockIdx.x * 128;
  f32x4 acc[4][4] = {};
  gemm_mainloop(xb, W, lA, lB, row0, col0, acc);
  const int lane = threadIdx.x & 63, wave = threadIdx.x >> 6;
  const int wr = wave >> 1, wc = wave & 1;
  // fold 1/sqrt(64) * log2(e) into Q so attention works in exp2 domain
  const float qs = (z == 0) ? 0.125f * 1.4426950408889634f : 1.0f;
#pragma unroll
  for (int m = 0; m < 4; ++m) {
#pragma unroll
    for (int n = 0; n < 4; ++n) {
      const int gr = row0 + wr * 64 + m * 16 + ((lane >> 4) << 2);
      const int gc = col0 + wc * 64 + n * 16 + (lane & 15);
      const int b = gr >> 11, t = gr & (T_ - 1);
      const int h = gc >> 6, d = gc & 63;
      if (z < 2) {
#pragma unroll
        for (int j = 0; j < 4; ++j)
          outb[(((size_t)(b * H_ + h)) * T_ + (t + j)) * D_ + d] =
              (bf16_t)(acc[m][n][j] * qs);
      } else {
        bf16x4 pk = {(bf16_t)acc[m][n][0], (bf16_t)acc[m][n][1],
                     (bf16_t)acc[m][n][2], (bf16_t)acc[m][n][3]};
        *(bf16x4*)(outb + (((size_t)(b * H_ + h)) * D_ + d) * T_ + t) = pk;
      }
    }
  }
}

// Output projection + bias, f32 out.
__global__ __launch_bounds__(256) void gemm_proj(const bf16_t* __restrict__ att,
                                                 const bf16_t* __restrict__ wp,
                                                 const float* __restrict__ bias,
                                                 float* __restrict__ out) {
  __shared__ bf16_t lA[128 * 64];
  __shared__ bf16_t lB[128 * 64];
  const int row0 = blockIdx.y * 128, col0 = blockIdx.x * 128;
  f32x4 acc[4][4] = {};
  gemm_mainloop(att, wp, lA, lB, row0, col0, acc);
  const int lane = threadIdx.x & 63, wave = threadIdx.x >> 6;
  const int wr = wave >> 1, wc = wave & 1;
#pragma unroll
  for (int m = 0; m < 4; ++m) {
#pragma unroll
    for (int n = 0; n < 4; ++n) {
      const int gr = row0 + wr * 64 + m * 16 + ((lane >> 4) << 2);
      const int gc = col0 + wc * 64 + n * 16 + (lane & 15);
      const float bv = bias[gc];
#pragma unroll
      for (int j = 0; j < 4; ++j)
        out[(size_t)(gr + j) * C_ + gc] = acc[m][n][j] + bv;
    }
  }
}

// --------------------------------------------------------- flash attention v6
// 64-row q-tile per block (16 rows/wave), paired (x, 31-x) over 32 q-tiles ->
// 1024 uniform blocks x 33 iters. LDS 40KB -> 4 blocks/CU = 16 waves/CU
// (2x TLP vs v5). Swapped QK^T: lane holds 16 scores of ONE q-row
// (q = lane&15, kv = nf*16 + g*4 + j); softmax = 15 local fmax + 2 shfl hops,
// single unconditional path, exp2 domain (Q pre-scaled by log2e/8).
__global__ __launch_bounds__(256) void attn_fwd(const bf16_t* __restrict__ Q,
                                                const bf16_t* __restrict__ K,
                                                const bf16_t* __restrict__ V,
                                                bf16_t* __restrict__ AO) {
  __shared__ bf16_t lK[2][64 * 64];
  __shared__ bf16_t lV[2][64 * 64];   // V^T tile: [d][s]
  __shared__ bf16_t lP[4][16 * 64];   // per-wave P re-layout buffer
  const int tid = threadIdx.x, wave = tid >> 6, lane = tid & 63;
  const int g = lane >> 4;            // 16-lane group id
  const int bh = blockIdx.y;
  const size_t baseK = (size_t)bh * T_ * D_;
  const size_t baseV = (size_t)bh * D_ * T_;
  const int bb = bh >> 4, hh = bh & 15;

  for (int half = 0; half < 2; ++half) {
    const int qt = half ? (31 - blockIdx.x) : blockIdx.x;
    const int tw = qt * 64;           // q rows [tw, tw+64); wave handles all
    const int ntiles = qt + 1;
    __syncthreads();  // protect LDS buffers from previous half's readers
    // prologue: stage tile 0 into buf 0
#pragma unroll
    for (int i = 0; i < 2; ++i) {
      const int off = (i * 4 + wave) * 1024;
      const int lin = off + lane * 16;
      const int r = lin >> 7;
      const int c = ((lin >> 4) & 7) ^ (r & 7);
      GLDS(K + baseK + (size_t)r * D_ + c * 8, &lK[0][off >> 1]);
      GLDS(V + baseV + (size_t)r * T_ + c * 8, &lV[0][off >> 1]);
    }
    // Q fragments for this wave's 16 rows (operand layout: row=lane&15,
    // k=g*8+e); Q pre-scaled by log2e/8. Waves share q-rows? No: each wave
    // owns rows tw + wave*16 .. +16.
    const int twv = tw + wave * 16;
    bf16x8 qf[2];
#pragma unroll
    for (int s = 0; s < 2; ++s)
      qf[s] = *(const bf16x8*)(Q + baseK +
                               (size_t)(twv + (lane & 15)) * D_ + s * 32 +
                               (g << 3));
    float mrun = -1e30f, lrun = 0.f;
    f32x4 o[4] = {};
    int cur = 0;
    for (int it = 0; it < ntiles; ++it) {
      __syncthreads();  // staging into `cur` complete; readers of cur^1 done
      if (it + 1 < ntiles) {
        const int s0n = (it + 1) * 64;
        const int nb = cur ^ 1;
#pragma unroll
        for (int i = 0; i < 2; ++i) {
          const int off = (i * 4 + wave) * 1024;
          const int lin = off + lane * 16;
          const int r = lin >> 7;
          const int c = ((lin >> 4) & 7) ^ (r & 7);
          GLDS(K + baseK + (size_t)(s0n + r) * D_ + c * 8, &lK[nb][off >> 1]);
          GLDS(V + baseV + (size_t)r * T_ + s0n + c * 8, &lV[nb][off >> 1]);
        }
      }
      const int s0 = it * 64;
      // S^T = K Q^T: rows kv (4 nf-frags), cols q (this wave's 16 rows)
      f32x4 sc[4];
#pragma unroll
      for (int nf = 0; nf < 4; ++nf) sc[nf] = (f32x4){};
      __builtin_amdgcn_s_setprio(1);
#pragma unroll
      for (int s = 0; s < 2; ++s) {
#pragma unroll
        for (int nf = 0; nf < 4; ++nf) {
          const int r = nf * 16 + (lane & 15);
          const int c = s * 4 + g;
          bf16x8 kf = *(const bf16x8*)((const char*)lK[cur] + r * 128 +
                                       ((c ^ (r & 7)) << 4));
          sc[nf] = mfma16(kf, qf[s], sc[nf]);  // swapped operands
        }
      }
      __builtin_amdgcn_s_setprio(0);
      // causal mask: only the diagonal tile (it == qt)
      if (it == qt) {
        const int t = twv + (lane & 15);
#pragma unroll
        for (int nf = 0; nf < 4; ++nf)
#pragma unroll
          for (int j = 0; j < 4; ++j) {
            const int s = s0 + nf * 16 + g * 4 + j;
            if (s > t) sc[nf][j] = -1e30f;
          }
      }
      // online softmax in exp2 domain; whole q-row lane-local + 2 hops
      float pmax = sc[0][0];
#pragma unroll
      for (int nf = 0; nf < 4; ++nf)
#pragma unroll
        for (int j = 0; j < 4; ++j) pmax = fmaxf(pmax, sc[nf][j]);
      pmax = fmaxf(pmax, __shfl_xor(pmax, 16));
      pmax = fmaxf(pmax, __shfl_xor(pmax, 32));
      const float mn = fmaxf(mrun, pmax);
      const float scl = exp2f(mrun - mn);
      mrun = mn;
      float ps = 0.f;
      bf16x4 pk[4];
#pragma unroll
      for (int nf = 0; nf < 4; ++nf)
#pragma unroll
        for (int j = 0; j < 4; ++j) {
          const float p = exp2f(sc[nf][j] - mn);
          ps += p;
          pk[nf][j] = (bf16_t)p;
        }
      ps += __shfl_xor(ps, 16);
      ps += __shfl_xor(ps, 32);
      lrun = lrun * scl + ps;
      // broadcast scl from q-col holders to O-row holders, rescale O
      float sb[4];
#pragma unroll
      for (int j = 0; j < 4; ++j)
        sb[j] = __shfl(scl, (lane & 48) | ((g << 2) + j));
#pragma unroll
      for (int df = 0; df < 4; ++df)
#pragma unroll
        for (int j = 0; j < 4; ++j) o[df][j] *= sb[j];
      // P -> LDS: row q (lane&15), packed bf16x4 per nf (XOR-16B involution)
      {
        const int r = lane & 15;
#pragma unroll
        for (int nf = 0; nf < 4; ++nf)
          *(bf16x4*)((char*)lP[wave] + r * 128 +
                     ((((2 * nf + (g >> 1)) ^ (r & 7)) << 4) |
                      ((g & 1) << 3))) = pk[nf];
      }
      // O += P V  (A = P rows q, B = V^T rows d, K = kv)
      __builtin_amdgcn_s_setprio(1);
#pragma unroll
      for (int s2 = 0; s2 < 2; ++s2) {
        const int cp = s2 * 4 + g;
        const int rp = lane & 15;
        bf16x8 pf = *(const bf16x8*)((const char*)lP[wave] + rp * 128 +
                                     ((cp ^ (rp & 7)) << 4));
#pragma unroll
        for (int df = 0; df < 4; ++df) {
          const int rv = df * 16 + (lane & 15);
          bf16x8 vf = *(const bf16x8*)((const char*)lV[cur] + rv * 128 +
                                       ((cp ^ (rv & 7)) << 4));
          o[df] = mfma16(pf, vf, o[df]);
        }
      }
      __builtin_amdgcn_s_setprio(0);
      cur ^= 1;
    }
    // epilogue: normalized O -> [B][T][C] bf16 (broadcast 1/l to row holders)
    {
      const float inv = 1.0f / lrun;
      float ib[4];
#pragma unroll
      for (int j = 0; j < 4; ++j)
        ib[j] = __shfl(inv, (lane & 48) | ((g << 2) + j));
#pragma unroll
      for (int j = 0; j < 4; ++j) {
        const int t = twv + (g << 2) + j;
#pragma unroll
        for (int df = 0; df < 4; ++df) {
          const int cc = hh * 64 + df * 16 + (lane & 15);
          AO[((size_t)(bb * T_ + t)) * C_ + cc] = (bf16_t)(o[df][j] * ib[j]);
        }
      }
    }
  }
}

// ---------------------------------------------------------------- launcher
extern "C" void kernel_launch(void* const* d_in, const int* in_sizes, int n_in,
                              void* d_out, int out_size, void* d_ws,
                              size_t ws_size, hipStream_t stream) {
  const float* x = (const float*)d_in[0];
  const float* Wk = (const float*)d_in[1];
  const float* Wq = (const float*)d_in[2];
  const float* Wv = (const float*)d_in[3];
  const float* Wp = (const float*)d_in[4];
  const float* bp = (const float*)d_in[5];
  char* ws = (char*)d_ws;
  // workspace layout (72 MiB):
  bf16_t* xb = (bf16_t*)ws;                          // 16 MiB (reused as att)
  bf16_t* wqb = (bf16_t*)(ws + (16u << 20));         // 2 MiB
  bf16_t* wkb = (bf16_t*)(ws + (18u << 20));         // 2 MiB
  bf16_t* wvb = (bf16_t*)(ws + (20u << 20));         // 2 MiB
  bf16_t* wpb = (bf16_t*)(ws + (22u << 20));         // 2 MiB
  bf16_t* q = (bf16_t*)(ws + (24u << 20));           // 16 MiB [B][H][T][D]
  bf16_t* k = (bf16_t*)(ws + (40u << 20));           // 16 MiB [B][H][T][D]
  bf16_t* vt = (bf16_t*)(ws + (56u << 20));          // 16 MiB [B][H][D][T]
  bf16_t* att = xb;  // x no longer needed once QKV GEMMs are done

  cvt_all<<<12288, 256, 0, stream>>>(x, Wq, Wk, Wv, Wp, xb, wqb, wkb, wvb, wpb);
  gemm_qkv<<<dim3(8, 64, 3), 256, 0, stream>>>(xb, wqb, wkb, wvb, q, k, vt);
  attn_fwd<<<dim3(16, 64), 256, 0, stream>>>(q, k, vt, att);
  gemm_proj<<<dim3(8, 64), 256, 0, stream>>>(att, wpb, bp, (float*)d_out);
}

// Round 7
// 215.817 us; speedup vs baseline: 1.0467x; 1.0467x over previous
//
#include <hip/hip_runtime.h>

typedef __bf16 bf16_t;
typedef bf16_t bf16x4 __attribute__((ext_vector_type(4)));
typedef bf16_t bf16x8 __attribute__((ext_vector_type(8)));
typedef float f32x4 __attribute__((ext_vector_type(4)));

#define B_ 4
#define T_ 2048
#define C_ 1024
#define H_ 16
#define D_ 64

// global -> LDS direct copy, 16B per lane; LDS dest must be wave-uniform base
// (HW adds lane*16). Source is per-lane (pre-swizzled to realize LDS swizzle).
#define GLDS(g, l)                                                          \
  __builtin_amdgcn_global_load_lds(                                         \
      (const __attribute__((address_space(1))) void*)(g),                   \
      (__attribute__((address_space(3))) void*)(l), 16, 0, 0)

static __device__ __forceinline__ f32x4 mfma16(bf16x8 a, bf16x8 b, f32x4 c) {
  return __builtin_amdgcn_mfma_f32_16x16x32_bf16(a, b, c, 0, 0, 0);
}

// ---------------------------------------------------------------- convert
// One launch converts x + the 4 weight matrices.
__global__ void cvt_all(const float* __restrict__ x, const float* __restrict__ wq,
                        const float* __restrict__ wk, const float* __restrict__ wv,
                        const float* __restrict__ wp, bf16_t* __restrict__ xb,
                        bf16_t* __restrict__ wqb, bf16_t* __restrict__ wkb,
                        bf16_t* __restrict__ wvb, bf16_t* __restrict__ wpb) {
  int i = blockIdx.x * blockDim.x + threadIdx.x;  // float4 index
  const float* src;
  bf16_t* dst;
  int off;
  if (i < 2097152) {
    src = x; dst = xb; off = i;
  } else {
    int r = i - 2097152;
    int region = r >> 18;  // 262144 float4 per weight
    off = r & 262143;
    if (region == 0) { src = wq; dst = wqb; }
    else if (region == 1) { src = wk; dst = wkb; }
    else if (region == 2) { src = wv; dst = wvb; }
    else { src = wp; dst = wpb; }
  }
  float4 v = ((const float4*)src)[off];
  bf16x4 o = {(bf16_t)v.x, (bf16_t)v.y, (bf16_t)v.z, (bf16_t)v.w};
  ((bf16x4*)dst)[off] = o;
}

// ------------------------------------------------------------ GEMM main loop
// C = A(MxK) * W(NxK)^T, 128x128 tile, BK=64, 256 threads = 2x2 waves,
// each wave 64x64 = 4x4 fragments of 16x16x32 bf16 MFMA.
// LDS tiles [128 rows][64 bf16] (128B rows), XOR-swizzled 16B chunks:
// phys_chunk = chunk ^ (row & 7). Staged linearly via global_load_lds with
// inverse-swizzled global source (same involution).
__device__ __forceinline__ void gemm_mainloop(const bf16_t* __restrict__ A,
                                              const bf16_t* __restrict__ W,
                                              bf16_t* lA, bf16_t* lB, int row0,
                                              int col0, f32x4 (&acc)[4][4]) {
  const int tid = threadIdx.x;
  const int wave = tid >> 6, lane = tid & 63;
  const int wr = wave >> 1, wc = wave & 1;
  for (int k0 = 0; k0 < C_; k0 += 64) {
#pragma unroll
    for (int it = 0; it < 4; ++it) {
      const int off = (it * 4 + wave) * 1024;  // bytes, wave-uniform
      const int lin = off + lane * 16;
      const int r = lin >> 7;
      const int c = ((lin >> 4) & 7) ^ (r & 7);
      GLDS(A + (size_t)(row0 + r) * C_ + k0 + c * 8, lA + (off >> 1));
      GLDS(W + (size_t)(col0 + r) * C_ + k0 + c * 8, lB + (off >> 1));
    }
    __syncthreads();
#pragma unroll
    for (int s = 0; s < 2; ++s) {
      bf16x8 af[4], bfr[4];
#pragma unroll
      for (int m = 0; m < 4; ++m) {
        const int r = wr * 64 + m * 16 + (lane & 15);
        const int c = s * 4 + (lane >> 4);
        af[m] = *(const bf16x8*)((const char*)lA + r * 128 +
                                 ((c ^ (r & 7)) << 4));
      }
#pragma unroll
      for (int n = 0; n < 4; ++n) {
        const int r = wc * 64 + n * 16 + (lane & 15);
        const int c = s * 4 + (lane >> 4);
        bfr[n] = *(const bf16x8*)((const char*)lB + r * 128 +
                                  ((c ^ (r & 7)) << 4));
      }
#pragma unroll
      for (int m = 0; m < 4; ++m)
#pragma unroll
        for (int n = 0; n < 4; ++n) acc[m][n] = mfma16(af[m], bfr[n], acc[m][n]);
    }
    __syncthreads();
  }
}

// QKV projection. z=0: Q (pre-scaled by log2(e)/sqrt(D)) -> [B][H][T][D];
// z=1: K -> [B][H][T][D]; z=2: V -> transposed [B][H][D][T].
__global__ __launch_bounds__(256) void gemm_qkv(
    const bf16_t* __restrict__ xb, const bf16_t* __restrict__ wq,
    const bf16_t* __restrict__ wk, const bf16_t* __restrict__ wv,
    bf16_t* __restrict__ qo, bf16_t* __restrict__ ko, bf16_t* __restrict__ vt) {
  __shared__ bf16_t lA[128 * 64];
  __shared__ bf16_t lB[128 * 64];
  const int z = blockIdx.z;
  const bf16_t* W = (z == 0) ? wq : ((z == 1) ? wk : wv);
  bf16_t* outb = (z == 0) ? qo : ((z == 1) ? ko : vt);
  const int row0 = blockIdx.y * 128, col0 = blockIdx.x * 128;
  f32x4 acc[4][4] = {};
  gemm_mainloop(xb, W, lA, lB, row0, col0, acc);
  const int lane = threadIdx.x & 63, wave = threadIdx.x >> 6;
  const int wr = wave >> 1, wc = wave & 1;
  // fold 1/sqrt(64) * log2(e) into Q so attention works in exp2 domain
  const float qs = (z == 0) ? 0.125f * 1.4426950408889634f : 1.0f;
#pragma unroll
  for (int m = 0; m < 4; ++m) {
#pragma unroll
    for (int n = 0; n < 4; ++n) {
      const int gr = row0 + wr * 64 + m * 16 + ((lane >> 4) << 2);
      const int gc = col0 + wc * 64 + n * 16 + (lane & 15);
      const int b = gr >> 11, t = gr & (T_ - 1);
      const int h = gc >> 6, d = gc & 63;
      if (z < 2) {
#pragma unroll
        for (int j = 0; j < 4; ++j)
          outb[(((size_t)(b * H_ + h)) * T_ + (t + j)) * D_ + d] =
              (bf16_t)(acc[m][n][j] * qs);
      } else {
        bf16x4 pk = {(bf16_t)acc[m][n][0], (bf16_t)acc[m][n][1],
                     (bf16_t)acc[m][n][2], (bf16_t)acc[m][n][3]};
        *(bf16x4*)(outb + (((size_t)(b * H_ + h)) * D_ + d) * T_ + t) = pk;
      }
    }
  }
}

// Output projection + bias, f32 out.
__global__ __launch_bounds__(256) void gemm_proj(const bf16_t* __restrict__ att,
                                                 const bf16_t* __restrict__ wp,
                                                 const float* __restrict__ bias,
                                                 float* __restrict__ out) {
  __shared__ bf16_t lA[128 * 64];
  __shared__ bf16_t lB[128 * 64];
  const int row0 = blockIdx.y * 128, col0 = blockIdx.x * 128;
  f32x4 acc[4][4] = {};
  gemm_mainloop(att, wp, lA, lB, row0, col0, acc);
  const int lane = threadIdx.x & 63, wave = threadIdx.x >> 6;
  const int wr = wave >> 1, wc = wave & 1;
#pragma unroll
  for (int m = 0; m < 4; ++m) {
#pragma unroll
    for (int n = 0; n < 4; ++n) {
      const int gr = row0 + wr * 64 + m * 16 + ((lane >> 4) << 2);
      const int gc = col0 + wc * 64 + n * 16 + (lane & 15);
      const float bv = bias[gc];
#pragma unroll
      for (int j = 0; j < 4; ++j)
        out[(size_t)(gr + j) * C_ + gc] = acc[m][n][j] + bv;
    }
  }
}

// --------------------------------------------------------- flash attention v7
// = r3's work-balanced paired schedule (q-tiles x and 15-x, 512 uniform
// blocks, 2/CU) + exp2 domain + vf-hoist. NO defer-max (single unconditional
// softmax path — r5's dual path duplicated the hot loop and regressed).
// Swapped QK^T: lane holds 16 scores of ONE q-row (q=lane&15,
// kv = nf*16 + g*4 + j); softmax = 15 local fmax + 2 shfl hops.
__global__ __launch_bounds__(256) void attn_fwd(const bf16_t* __restrict__ Q,
                                                const bf16_t* __restrict__ K,
                                                const bf16_t* __restrict__ V,
                                                bf16_t* __restrict__ AO) {
  __shared__ bf16_t lK[2][64 * 64];
  __shared__ bf16_t lV[2][64 * 64];   // V^T tile: [d][s]
  __shared__ bf16_t lP[4][32 * 64];   // per-wave P re-layout buffer
  const int tid = threadIdx.x, wave = tid >> 6, lane = tid & 63;
  const int g = lane >> 4;            // 16-lane group id
  const int bh = blockIdx.y;
  const size_t baseK = (size_t)bh * T_ * D_;
  const size_t baseV = (size_t)bh * D_ * T_;
  const int bb = bh >> 4, hh = bh & 15;

  for (int half = 0; half < 2; ++half) {
    const int qt = half ? (15 - blockIdx.x) : blockIdx.x;
    const int tw = qt * 128 + wave * 32;
    const int ntiles = 2 * qt + 2;
    __syncthreads();  // protect LDS buffers from previous half's readers
    // prologue: stage tile 0 into buf 0
#pragma unroll
    for (int i = 0; i < 2; ++i) {
      const int off = (i * 4 + wave) * 1024;
      const int lin = off + lane * 16;
      const int r = lin >> 7;
      const int c = ((lin >> 4) & 7) ^ (r & 7);
      GLDS(K + baseK + (size_t)r * D_ + c * 8, &lK[0][off >> 1]);
      GLDS(V + baseV + (size_t)r * T_ + c * 8, &lV[0][off >> 1]);
    }
    // Q fragments (operand layout: row=lane&15, k=g*8+e); Q pre-scaled by
    // log2e/8 in the QKV GEMM.
    bf16x8 qf[2][2];
#pragma unroll
    for (int m = 0; m < 2; ++m)
#pragma unroll
      for (int s = 0; s < 2; ++s)
        qf[m][s] = *(const bf16x8*)(Q + baseK +
                                    (size_t)(tw + 16 * m + (lane & 15)) * D_ +
                                    s * 32 + (g << 3));
    float mrun[2], lrun[2];
    f32x4 o[2][4] = {};
#pragma unroll
    for (int m = 0; m < 2; ++m) {
      mrun[m] = -1e30f;
      lrun[m] = 0.f;
    }
    int cur = 0;
    for (int it = 0; it < ntiles; ++it) {
      __syncthreads();  // staging into `cur` complete; readers of cur^1 done
      if (it + 1 < ntiles) {
        const int s0n = (it + 1) * 64;
        const int nb = cur ^ 1;
#pragma unroll
        for (int i = 0; i < 2; ++i) {
          const int off = (i * 4 + wave) * 1024;
          const int lin = off + lane * 16;
          const int r = lin >> 7;
          const int c = ((lin >> 4) & 7) ^ (r & 7);
          GLDS(K + baseK + (size_t)(s0n + r) * D_ + c * 8, &lK[nb][off >> 1]);
          GLDS(V + baseV + (size_t)r * T_ + s0n + c * 8, &lV[nb][off >> 1]);
        }
      }
      const int s0 = it * 64;
      // S^T = K Q^T per wave: rows kv (4 nf-frags), cols q (2 m-frags)
      f32x4 sc[2][4];
#pragma unroll
      for (int m = 0; m < 2; ++m)
#pragma unroll
        for (int nf = 0; nf < 4; ++nf) sc[m][nf] = (f32x4){};
      __builtin_amdgcn_s_setprio(1);
#pragma unroll
      for (int s = 0; s < 2; ++s) {
#pragma unroll
        for (int nf = 0; nf < 4; ++nf) {
          const int r = nf * 16 + (lane & 15);
          const int c = s * 4 + g;
          bf16x8 kf = *(const bf16x8*)((const char*)lK[cur] + r * 128 +
                                       ((c ^ (r & 7)) << 4));
#pragma unroll
          for (int m = 0; m < 2; ++m)
            sc[m][nf] = mfma16(kf, qf[m][s], sc[m][nf]);  // swapped operands
        }
      }
      __builtin_amdgcn_s_setprio(0);
      // causal mask (only the last two tiles touch the diagonal)
      if (it >= 2 * qt) {
#pragma unroll
        for (int m = 0; m < 2; ++m) {
          const int t = tw + 16 * m + (lane & 15);
#pragma unroll
          for (int nf = 0; nf < 4; ++nf)
#pragma unroll
            for (int j = 0; j < 4; ++j) {
              const int s = s0 + nf * 16 + g * 4 + j;
              if (s > t) sc[m][nf][j] = -1e30f;
            }
        }
      }
      // online softmax in exp2 domain; whole q-row lane-local + 2 hops
#pragma unroll
      for (int m = 0; m < 2; ++m) {
        float pmax = sc[m][0][0];
#pragma unroll
        for (int nf = 0; nf < 4; ++nf)
#pragma unroll
          for (int j = 0; j < 4; ++j) pmax = fmaxf(pmax, sc[m][nf][j]);
        pmax = fmaxf(pmax, __shfl_xor(pmax, 16));
        pmax = fmaxf(pmax, __shfl_xor(pmax, 32));
        const float mn = fmaxf(mrun[m], pmax);
        const float scl = exp2f(mrun[m] - mn);
        mrun[m] = mn;
        float ps = 0.f;
        bf16x4 pk[4];
#pragma unroll
        for (int nf = 0; nf < 4; ++nf)
#pragma unroll
          for (int j = 0; j < 4; ++j) {
            const float p = exp2f(sc[m][nf][j] - mn);
            ps += p;
            pk[nf][j] = (bf16_t)p;
          }
        ps += __shfl_xor(ps, 16);
        ps += __shfl_xor(ps, 32);
        lrun[m] = lrun[m] * scl + ps;
        // broadcast scl from q-col holders to O-row holders, rescale O
        float sb[4];
#pragma unroll
        for (int j = 0; j < 4; ++j)
          sb[j] = __shfl(scl, (lane & 48) | ((g << 2) + j));
#pragma unroll
        for (int df = 0; df < 4; ++df)
#pragma unroll
          for (int j = 0; j < 4; ++j) o[m][df][j] *= sb[j];
        // P -> LDS: row q, packed bf16x4 per nf (same XOR-16B involution)
        const int r = 16 * m + (lane & 15);
#pragma unroll
        for (int nf = 0; nf < 4; ++nf)
          *(bf16x4*)((char*)lP[wave] + r * 128 +
                     ((((2 * nf + (g >> 1)) ^ (r & 7)) << 4) | ((g & 1) << 3))) =
              pk[nf];
      }
      // O += P V  (A = P rows q, B = V^T rows d, K = kv); V-frags hoisted
      __builtin_amdgcn_s_setprio(1);
#pragma unroll
      for (int s2 = 0; s2 < 2; ++s2) {
        const int cp = s2 * 4 + g;
        bf16x8 pf[2];
#pragma unroll
        for (int m = 0; m < 2; ++m) {
          const int rp = 16 * m + (lane & 15);
          pf[m] = *(const bf16x8*)((const char*)lP[wave] + rp * 128 +
                                   ((cp ^ (rp & 7)) << 4));
        }
#pragma unroll
        for (int df = 0; df < 4; ++df) {
          const int rv = df * 16 + (lane & 15);
          bf16x8 vf = *(const bf16x8*)((const char*)lV[cur] + rv * 128 +
                                       ((cp ^ (rv & 7)) << 4));
#pragma unroll
          for (int m = 0; m < 2; ++m) o[m][df] = mfma16(pf[m], vf, o[m][df]);
        }
      }
      __builtin_amdgcn_s_setprio(0);
      cur ^= 1;
    }
    // epilogue: normalized O -> [B][T][C] bf16 (broadcast 1/l to row holders)
#pragma unroll
    for (int m = 0; m < 2; ++m) {
      const float inv = 1.0f / lrun[m];
      float ib[4];
#pragma unroll
      for (int j = 0; j < 4; ++j)
        ib[j] = __shfl(inv, (lane & 48) | ((g << 2) + j));
#pragma unroll
      for (int j = 0; j < 4; ++j) {
        const int t = tw + 16 * m + (g << 2) + j;
#pragma unroll
        for (int df = 0; df < 4; ++df) {
          const int cc = hh * 64 + df * 16 + (lane & 15);
          AO[((size_t)(bb * T_ + t)) * C_ + cc] = (bf16_t)(o[m][df][j] * ib[j]);
        }
      }
    }
  }
}

// ---------------------------------------------------------------- launcher
extern "C" void kernel_launch(void* const* d_in, const int* in_sizes, int n_in,
                              void* d_out, int out_size, void* d_ws,
                              size_t ws_size, hipStream_t stream) {
  const float* x = (const float*)d_in[0];
  const float* Wk = (const float*)d_in[1];
  const float* Wq = (const float*)d_in[2];
  const float* Wv = (const float*)d_in[3];
  const float* Wp = (const float*)d_in[4];
  const float* bp = (const float*)d_in[5];
  char* ws = (char*)d_ws;
  // workspace layout (72 MiB):
  bf16_t* xb = (bf16_t*)ws;                          // 16 MiB (reused as att)
  bf16_t* wqb = (bf16_t*)(ws + (16u << 20));         // 2 MiB
  bf16_t* wkb = (bf16_t*)(ws + (18u << 20));         // 2 MiB
  bf16_t* wvb = (bf16_t*)(ws + (20u << 20));         // 2 MiB
  bf16_t* wpb = (bf16_t*)(ws + (22u << 20));         // 2 MiB
  bf16_t* q = (bf16_t*)(ws + (24u << 20));           // 16 MiB [B][H][T][D]
  bf16_t* k = (bf16_t*)(ws + (40u << 20));           // 16 MiB [B][H][T][D]
  bf16_t* vt = (bf16_t*)(ws + (56u << 20));          // 16 MiB [B][H][D][T]
  bf16_t* att = xb;  // x no longer needed once QKV GEMMs are done

  cvt_all<<<12288, 256, 0, stream>>>(x, Wq, Wk, Wv, Wp, xb, wqb, wkb, wvb, wpb);
  gemm_qkv<<<dim3(8, 64, 3), 256, 0, stream>>>(xb, wqb, wkb, wvb, q, k, vt);
  attn_fwd<<<dim3(8, 64), 256, 0, stream>>>(q, k, vt, att);
  gemm_proj<<<dim3(8, 64), 256, 0, stream>>>(att, wpb, bp, (float*)d_out);
}

// Round 8
// 191.060 us; speedup vs baseline: 1.1823x; 1.1296x over previous
//
#include <hip/hip_runtime.h>

typedef __bf16 bf16_t;
typedef bf16_t bf16x4 __attribute__((ext_vector_type(4)));
typedef bf16_t bf16x8 __attribute__((ext_vector_type(8)));
typedef float f32x4 __attribute__((ext_vector_type(4)));

#define B_ 4
#define T_ 2048
#define C_ 1024
#define H_ 16
#define D_ 64

// global -> LDS direct copy, 16B per lane; LDS dest must be wave-uniform base
// (HW adds lane*16). Source is per-lane (pre-swizzled to realize LDS swizzle).
#define GLDS(g, l)                                                          \
  __builtin_amdgcn_global_load_lds(                                         \
      (const __attribute__((address_space(1))) void*)(g),                   \
      (__attribute__((address_space(3))) void*)(l), 16, 0, 0)

static __device__ __forceinline__ f32x4 mfma16(bf16x8 a, bf16x8 b, f32x4 c) {
  return __builtin_amdgcn_mfma_f32_16x16x32_bf16(a, b, c, 0, 0, 0);
}

// ---------------------------------------------------------------- convert
// One launch converts x + the 4 weight matrices.
__global__ void cvt_all(const float* __restrict__ x, const float* __restrict__ wq,
                        const float* __restrict__ wk, const float* __restrict__ wv,
                        const float* __restrict__ wp, bf16_t* __restrict__ xb,
                        bf16_t* __restrict__ wqb, bf16_t* __restrict__ wkb,
                        bf16_t* __restrict__ wvb, bf16_t* __restrict__ wpb) {
  int i = blockIdx.x * blockDim.x + threadIdx.x;  // float4 index
  const float* src;
  bf16_t* dst;
  int off;
  if (i < 2097152) {
    src = x; dst = xb; off = i;
  } else {
    int r = i - 2097152;
    int region = r >> 18;  // 262144 float4 per weight
    off = r & 262143;
    if (region == 0) { src = wq; dst = wqb; }
    else if (region == 1) { src = wk; dst = wkb; }
    else if (region == 2) { src = wv; dst = wvb; }
    else { src = wp; dst = wpb; }
  }
  float4 v = ((const float4*)src)[off];
  bf16x4 o = {(bf16_t)v.x, (bf16_t)v.y, (bf16_t)v.z, (bf16_t)v.w};
  ((bf16x4*)dst)[off] = o;
}

// ------------------------------------------------------------ GEMM main loop
// C = A(MxK) * W(NxK)^T, 128x128 tile, BK=64, 256 threads = 2x2 waves,
// each wave 64x64 = 4x4 fragments of 16x16x32 bf16 MFMA.
// LDS tiles [128 rows][64 bf16] (128B rows), XOR-swizzled 16B chunks:
// phys_chunk = chunk ^ (row & 7). Staged linearly via global_load_lds with
// inverse-swizzled global source (same involution).
__device__ __forceinline__ void gemm_mainloop(const bf16_t* __restrict__ A,
                                              const bf16_t* __restrict__ W,
                                              bf16_t* lA, bf16_t* lB, int row0,
                                              int col0, f32x4 (&acc)[4][4]) {
  const int tid = threadIdx.x;
  const int wave = tid >> 6, lane = tid & 63;
  const int wr = wave >> 1, wc = wave & 1;
  for (int k0 = 0; k0 < C_; k0 += 64) {
#pragma unroll
    for (int it = 0; it < 4; ++it) {
      const int off = (it * 4 + wave) * 1024;  // bytes, wave-uniform
      const int lin = off + lane * 16;
      const int r = lin >> 7;
      const int c = ((lin >> 4) & 7) ^ (r & 7);
      GLDS(A + (size_t)(row0 + r) * C_ + k0 + c * 8, lA + (off >> 1));
      GLDS(W + (size_t)(col0 + r) * C_ + k0 + c * 8, lB + (off >> 1));
    }
    __syncthreads();
#pragma unroll
    for (int s = 0; s < 2; ++s) {
      bf16x8 af[4], bfr[4];
#pragma unroll
      for (int m = 0; m < 4; ++m) {
        const int r = wr * 64 + m * 16 + (lane & 15);
        const int c = s * 4 + (lane >> 4);
        af[m] = *(const bf16x8*)((const char*)lA + r * 128 +
                                 ((c ^ (r & 7)) << 4));
      }
#pragma unroll
      for (int n = 0; n < 4; ++n) {
        const int r = wc * 64 + n * 16 + (lane & 15);
        const int c = s * 4 + (lane >> 4);
        bfr[n] = *(const bf16x8*)((const char*)lB + r * 128 +
                                  ((c ^ (r & 7)) << 4));
      }
#pragma unroll
      for (int m = 0; m < 4; ++m)
#pragma unroll
        for (int n = 0; n < 4; ++n) acc[m][n] = mfma16(af[m], bfr[n], acc[m][n]);
    }
    __syncthreads();
  }
}

// QKV projection. z=0: Q (pre-scaled by 1/sqrt(D)) -> [B][H][T][D];
// z=1: K -> [B][H][T][D]; z=2: V -> transposed [B][H][D][T].
__global__ __launch_bounds__(256) void gemm_qkv(
    const bf16_t* __restrict__ xb, const bf16_t* __restrict__ wq,
    const bf16_t* __restrict__ wk, const bf16_t* __restrict__ wv,
    bf16_t* __restrict__ qo, bf16_t* __restrict__ ko, bf16_t* __restrict__ vt) {
  __shared__ bf16_t lA[128 * 64];
  __shared__ bf16_t lB[128 * 64];
  const int z = blockIdx.z;
  const bf16_t* W = (z == 0) ? wq : ((z == 1) ? wk : wv);
  bf16_t* outb = (z == 0) ? qo : ((z == 1) ? ko : vt);
  const int row0 = blockIdx.y * 128, col0 = blockIdx.x * 128;
  f32x4 acc[4][4] = {};
  gemm_mainloop(xb, W, lA, lB, row0, col0, acc);
  const int lane = threadIdx.x & 63, wave = threadIdx.x >> 6;
  const int wr = wave >> 1, wc = wave & 1;
  const float qs = (z == 0) ? 0.125f : 1.0f;  // fold 1/sqrt(64) into Q
#pragma unroll
  for (int m = 0; m < 4; ++m) {
#pragma unroll
    for (int n = 0; n < 4; ++n) {
      const int gr = row0 + wr * 64 + m * 16 + ((lane >> 4) << 2);
      const int gc = col0 + wc * 64 + n * 16 + (lane & 15);
      const int b = gr >> 11, t = gr & (T_ - 1);
      const int h = gc >> 6, d = gc & 63;
      if (z < 2) {
#pragma unroll
        for (int j = 0; j < 4; ++j)
          outb[(((size_t)(b * H_ + h)) * T_ + (t + j)) * D_ + d] =
              (bf16_t)(acc[m][n][j] * qs);
      } else {
        bf16x4 pk = {(bf16_t)acc[m][n][0], (bf16_t)acc[m][n][1],
                     (bf16_t)acc[m][n][2], (bf16_t)acc[m][n][3]};
        *(bf16x4*)(outb + (((size_t)(b * H_ + h)) * D_ + d) * T_ + t) = pk;
      }
    }
  }
}

// Output projection + bias, f32 out.
__global__ __launch_bounds__(256) void gemm_proj(const bf16_t* __restrict__ att,
                                                 const bf16_t* __restrict__ wp,
                                                 const float* __restrict__ bias,
                                                 float* __restrict__ out) {
  __shared__ bf16_t lA[128 * 64];
  __shared__ bf16_t lB[128 * 64];
  const int row0 = blockIdx.y * 128, col0 = blockIdx.x * 128;
  f32x4 acc[4][4] = {};
  gemm_mainloop(att, wp, lA, lB, row0, col0, acc);
  const int lane = threadIdx.x & 63, wave = threadIdx.x >> 6;
  const int wr = wave >> 1, wc = wave & 1;
#pragma unroll
  for (int m = 0; m < 4; ++m) {
#pragma unroll
    for (int n = 0; n < 4; ++n) {
      const int gr = row0 + wr * 64 + m * 16 + ((lane >> 4) << 2);
      const int gc = col0 + wc * 64 + n * 16 + (lane & 15);
      const float bv = bias[gc];
#pragma unroll
      for (int j = 0; j < 4; ++j)
        out[(size_t)(gr + j) * C_ + gc] = acc[m][n][j] + bv;
    }
  }
}

// --------------------------------------------------------- flash attention v8
// 8 waves x 16 q-rows = 128-row q-tile per block; paired (x, 15-x) -> 512
// uniform blocks x 34 iters, 2 blocks/CU = 16 waves/CU (4/SIMD — 2x TLP vs
// the 4-wave variant at identical KV traffic). Softmax = r3's proven __expf
// path (exp2f regressed: +7% VALUBusy, not a bare v_exp). Swapped QK^T: lane
// holds 16 scores of ONE q-row (q=lane&15, kv = nf*16+g*4+j); 15 local fmax
// + 2 shfl hops.
__global__ __launch_bounds__(512, 4) void attn_fwd(
    const bf16_t* __restrict__ Q, const bf16_t* __restrict__ K,
    const bf16_t* __restrict__ V, bf16_t* __restrict__ AO) {
  __shared__ bf16_t lK[2][64 * 64];
  __shared__ bf16_t lV[2][64 * 64];   // V^T tile: [d][s]
  __shared__ bf16_t lP[8][16 * 64];   // per-wave P re-layout buffer
  const int tid = threadIdx.x, wave = tid >> 6, lane = tid & 63;
  const int g = lane >> 4;            // 16-lane group id
  const int bh = blockIdx.y;
  const size_t baseK = (size_t)bh * T_ * D_;
  const size_t baseV = (size_t)bh * D_ * T_;
  const int bb = bh >> 4, hh = bh & 15;

  for (int half = 0; half < 2; ++half) {
    const int qt = half ? (15 - blockIdx.x) : blockIdx.x;
    const int twv = qt * 128 + wave * 16;  // this wave's 16 q-rows
    const int ntiles = 2 * qt + 2;
    __syncthreads();  // protect LDS buffers from previous half's readers
    // prologue: stage tile 0 into buf 0 (each wave stages 1KB per buffer)
    {
      const int off = wave * 1024;
      const int lin = off + lane * 16;
      const int r = lin >> 7;
      const int c = ((lin >> 4) & 7) ^ (r & 7);
      GLDS(K + baseK + (size_t)r * D_ + c * 8, &lK[0][off >> 1]);
      GLDS(V + baseV + (size_t)r * T_ + c * 8, &lV[0][off >> 1]);
    }
    // Q fragments (operand layout: row=lane&15, k=g*8+e); Q pre-scaled 0.125.
    bf16x8 qf[2];
#pragma unroll
    for (int s = 0; s < 2; ++s)
      qf[s] = *(const bf16x8*)(Q + baseK +
                               (size_t)(twv + (lane & 15)) * D_ + s * 32 +
                               (g << 3));
    float mrun = -1e30f, lrun = 0.f;
    f32x4 o[4] = {};
    int cur = 0;
    for (int it = 0; it < ntiles; ++it) {
      __syncthreads();  // staging into `cur` complete; readers of cur^1 done
      if (it + 1 < ntiles) {
        const int s0n = (it + 1) * 64;
        const int nb = cur ^ 1;
        const int off = wave * 1024;
        const int lin = off + lane * 16;
        const int r = lin >> 7;
        const int c = ((lin >> 4) & 7) ^ (r & 7);
        GLDS(K + baseK + (size_t)(s0n + r) * D_ + c * 8, &lK[nb][off >> 1]);
        GLDS(V + baseV + (size_t)r * T_ + s0n + c * 8, &lV[nb][off >> 1]);
      }
      const int s0 = it * 64;
      // S^T = K Q^T: rows kv (4 nf-frags), cols q (this wave's 16 rows)
      f32x4 sc[4];
#pragma unroll
      for (int nf = 0; nf < 4; ++nf) sc[nf] = (f32x4){};
      __builtin_amdgcn_s_setprio(1);
#pragma unroll
      for (int s = 0; s < 2; ++s) {
#pragma unroll
        for (int nf = 0; nf < 4; ++nf) {
          const int r = nf * 16 + (lane & 15);
          const int c = s * 4 + g;
          bf16x8 kf = *(const bf16x8*)((const char*)lK[cur] + r * 128 +
                                       ((c ^ (r & 7)) << 4));
          sc[nf] = mfma16(kf, qf[s], sc[nf]);  // swapped operands
        }
      }
      __builtin_amdgcn_s_setprio(0);
      // causal mask (only the last two tiles touch the diagonal)
      if (it >= 2 * qt) {
        const int t = twv + (lane & 15);
#pragma unroll
        for (int nf = 0; nf < 4; ++nf)
#pragma unroll
          for (int j = 0; j < 4; ++j) {
            const int s = s0 + nf * 16 + g * 4 + j;
            if (s > t) sc[nf][j] = -1e30f;
          }
      }
      // online softmax (r3 form); whole q-row lane-local + 2 hops
      float pmax = sc[0][0];
#pragma unroll
      for (int nf = 0; nf < 4; ++nf)
#pragma unroll
        for (int j = 0; j < 4; ++j) pmax = fmaxf(pmax, sc[nf][j]);
      pmax = fmaxf(pmax, __shfl_xor(pmax, 16));
      pmax = fmaxf(pmax, __shfl_xor(pmax, 32));
      const float mn = fmaxf(mrun, pmax);
      const float scl = __expf(mrun - mn);
      mrun = mn;
      float ps = 0.f;
      bf16x4 pk[4];
#pragma unroll
      for (int nf = 0; nf < 4; ++nf)
#pragma unroll
        for (int j = 0; j < 4; ++j) {
          const float p = __expf(sc[nf][j] - mn);
          ps += p;
          pk[nf][j] = (bf16_t)p;
        }
      ps += __shfl_xor(ps, 16);
      ps += __shfl_xor(ps, 32);
      lrun = lrun * scl + ps;
      // broadcast scl from q-col holders to O-row holders, rescale O
      float sb[4];
#pragma unroll
      for (int j = 0; j < 4; ++j)
        sb[j] = __shfl(scl, (lane & 48) | ((g << 2) + j));
#pragma unroll
      for (int df = 0; df < 4; ++df)
#pragma unroll
        for (int j = 0; j < 4; ++j) o[df][j] *= sb[j];
      // P -> LDS: row q (lane&15), packed bf16x4 per nf (XOR-16B involution)
      {
        const int r = lane & 15;
#pragma unroll
        for (int nf = 0; nf < 4; ++nf)
          *(bf16x4*)((char*)lP[wave] + r * 128 +
                     ((((2 * nf + (g >> 1)) ^ (r & 7)) << 4) |
                      ((g & 1) << 3))) = pk[nf];
      }
      // O += P V  (A = P rows q, B = V^T rows d, K = kv)
      __builtin_amdgcn_s_setprio(1);
#pragma unroll
      for (int s2 = 0; s2 < 2; ++s2) {
        const int cp = s2 * 4 + g;
        const int rp = lane & 15;
        bf16x8 pf = *(const bf16x8*)((const char*)lP[wave] + rp * 128 +
                                     ((cp ^ (rp & 7)) << 4));
#pragma unroll
        for (int df = 0; df < 4; ++df) {
          const int rv = df * 16 + (lane & 15);
          bf16x8 vf = *(const bf16x8*)((const char*)lV[cur] + rv * 128 +
                                       ((cp ^ (rv & 7)) << 4));
          o[df] = mfma16(pf, vf, o[df]);
        }
      }
      __builtin_amdgcn_s_setprio(0);
      cur ^= 1;
    }
    // epilogue: normalized O -> [B][T][C] bf16 (broadcast 1/l to row holders)
    {
      const float inv = 1.0f / lrun;
      float ib[4];
#pragma unroll
      for (int j = 0; j < 4; ++j)
        ib[j] = __shfl(inv, (lane & 48) | ((g << 2) + j));
#pragma unroll
      for (int j = 0; j < 4; ++j) {
        const int t = twv + (g << 2) + j;
#pragma unroll
        for (int df = 0; df < 4; ++df) {
          const int cc = hh * 64 + df * 16 + (lane & 15);
          AO[((size_t)(bb * T_ + t)) * C_ + cc] = (bf16_t)(o[df][j] * ib[j]);
        }
      }
    }
  }
}

// ---------------------------------------------------------------- launcher
extern "C" void kernel_launch(void* const* d_in, const int* in_sizes, int n_in,
                              void* d_out, int out_size, void* d_ws,
                              size_t ws_size, hipStream_t stream) {
  const float* x = (const float*)d_in[0];
  const float* Wk = (const float*)d_in[1];
  const float* Wq = (const float*)d_in[2];
  const float* Wv = (const float*)d_in[3];
  const float* Wp = (const float*)d_in[4];
  const float* bp = (const float*)d_in[5];
  char* ws = (char*)d_ws;
  // workspace layout (72 MiB):
  bf16_t* xb = (bf16_t*)ws;                          // 16 MiB (reused as att)
  bf16_t* wqb = (bf16_t*)(ws + (16u << 20));         // 2 MiB
  bf16_t* wkb = (bf16_t*)(ws + (18u << 20));         // 2 MiB
  bf16_t* wvb = (bf16_t*)(ws + (20u << 20));         // 2 MiB
  bf16_t* wpb = (bf16_t*)(ws + (22u << 20));         // 2 MiB
  bf16_t* q = (bf16_t*)(ws + (24u << 20));           // 16 MiB [B][H][T][D]
  bf16_t* k = (bf16_t*)(ws + (40u << 20));           // 16 MiB [B][H][T][D]
  bf16_t* vt = (bf16_t*)(ws + (56u << 20));          // 16 MiB [B][H][D][T]
  bf16_t* att = xb;  // x no longer needed once QKV GEMMs are done

  cvt_all<<<12288, 256, 0, stream>>>(x, Wq, Wk, Wv, Wp, xb, wqb, wkb, wvb, wpb);
  gemm_qkv<<<dim3(8, 64, 3), 256, 0, stream>>>(xb, wqb, wkb, wvb, q, k, vt);
  attn_fwd<<<dim3(8, 64), 512, 0, stream>>>(q, k, vt, att);
  gemm_proj<<<dim3(8, 64), 256, 0, stream>>>(att, wpb, bp, (float*)d_out);
}

// Round 9
// 179.821 us; speedup vs baseline: 1.2562x; 1.0625x over previous
//
#include <hip/hip_runtime.h>

typedef __bf16 bf16_t;
typedef bf16_t bf16x4 __attribute__((ext_vector_type(4)));
typedef bf16_t bf16x8 __attribute__((ext_vector_type(8)));
typedef float f32x4 __attribute__((ext_vector_type(4)));

#define B_ 4
#define T_ 2048
#define C_ 1024
#define H_ 16
#define D_ 64

// global -> LDS direct copy, 16B per lane; LDS dest must be wave-uniform base
// (HW adds lane*16). Source is per-lane (pre-swizzled to realize LDS swizzle).
#define GLDS(g, l)                                                          \
  __builtin_amdgcn_global_load_lds(                                         \
      (const __attribute__((address_space(1))) void*)(g),                   \
      (__attribute__((address_space(3))) void*)(l), 16, 0, 0)

static __device__ __forceinline__ f32x4 mfma16(bf16x8 a, bf16x8 b, f32x4 c) {
  return __builtin_amdgcn_mfma_f32_16x16x32_bf16(a, b, c, 0, 0, 0);
}

// ---------------------------------------------------------------- convert
// One launch converts x + the 4 weight matrices.
__global__ void cvt_all(const float* __restrict__ x, const float* __restrict__ wq,
                        const float* __restrict__ wk, const float* __restrict__ wv,
                        const float* __restrict__ wp, bf16_t* __restrict__ xb,
                        bf16_t* __restrict__ wqb, bf16_t* __restrict__ wkb,
                        bf16_t* __restrict__ wvb, bf16_t* __restrict__ wpb) {
  int i = blockIdx.x * blockDim.x + threadIdx.x;  // float4 index
  const float* src;
  bf16_t* dst;
  int off;
  if (i < 2097152) {
    src = x; dst = xb; off = i;
  } else {
    int r = i - 2097152;
    int region = r >> 18;  // 262144 float4 per weight
    off = r & 262143;
    if (region == 0) { src = wq; dst = wqb; }
    else if (region == 1) { src = wk; dst = wkb; }
    else if (region == 2) { src = wv; dst = wvb; }
    else { src = wp; dst = wpb; }
  }
  float4 v = ((const float4*)src)[off];
  bf16x4 o = {(bf16_t)v.x, (bf16_t)v.y, (bf16_t)v.z, (bf16_t)v.w};
  ((bf16x4*)dst)[off] = o;
}

// --------------------------------------------- fused QKV GEMM (z inside)
// One block computes the SAME 128x128 output tile for Q, K and V:
// A-tile (x rows) staged ONCE per k-step and its ds_reads shared across the
// 3 B-operands -> 20 ds_read_b128 per 48 MFMA per wave-k-step (vs 8/16),
// staging bytes/MFMA -33%, x HBM traffic /3. 512 threads = 8 waves (2 row x
// 4 col), wave tile 64x32 per z, acc[3][4][2]. LDS = A + 3xB = 64KB.
// XCD-chunked swizzle: consecutive 64-block chunk (8 row-panels x 8 col
// tiles) per XCD for A-panel L2 reuse.
// z=0: Q (pre-scaled 1/8) -> [B][H][T][D]; z=1: K -> [B][H][T][D];
// z=2: V -> transposed [B][H][D][T].
__global__ __launch_bounds__(512) void gemm_qkv(
    const bf16_t* __restrict__ xb, const bf16_t* __restrict__ wq,
    const bf16_t* __restrict__ wk, const bf16_t* __restrict__ wv,
    bf16_t* __restrict__ qo, bf16_t* __restrict__ ko, bf16_t* __restrict__ vt) {
  __shared__ bf16_t lA[128 * 64];
  __shared__ bf16_t lB[3][128 * 64];
  const int tid = threadIdx.x, wave = tid >> 6, lane = tid & 63;
  const int g = lane >> 4;
  const int bid = blockIdx.x;
  const int swz = ((bid & 7) << 6) | (bid >> 3);  // 64-block chunk per XCD
  const int col0 = (swz & 7) * 128, row0 = (swz >> 3) * 128;
  const int wr = wave >> 2, wc = wave & 3;  // 2 x 4 wave grid
  f32x4 acc[3][4][2] = {};
  for (int k0 = 0; k0 < C_; k0 += 64) {
#pragma unroll
    for (int i = 0; i < 2; ++i) {
      const int off = (i * 8 + wave) * 1024;  // bytes, wave-uniform
      const int lin = off + lane * 16;
      const int r = lin >> 7;
      const int c = ((lin >> 4) & 7) ^ (r & 7);
      GLDS(xb + (size_t)(row0 + r) * C_ + k0 + c * 8, lA + (off >> 1));
      GLDS(wq + (size_t)(col0 + r) * C_ + k0 + c * 8, &lB[0][off >> 1]);
      GLDS(wk + (size_t)(col0 + r) * C_ + k0 + c * 8, &lB[1][off >> 1]);
      GLDS(wv + (size_t)(col0 + r) * C_ + k0 + c * 8, &lB[2][off >> 1]);
    }
    __syncthreads();
#pragma unroll
    for (int s = 0; s < 2; ++s) {
      const int c = s * 4 + g;
      bf16x8 af[4];
#pragma unroll
      for (int m = 0; m < 4; ++m) {
        const int r = wr * 64 + m * 16 + (lane & 15);
        af[m] = *(const bf16x8*)((const char*)lA + r * 128 +
                                 ((c ^ (r & 7)) << 4));
      }
#pragma unroll
      for (int z = 0; z < 3; ++z) {
        bf16x8 bfr[2];
#pragma unroll
        for (int n = 0; n < 2; ++n) {
          const int r = wc * 32 + n * 16 + (lane & 15);
          bfr[n] = *(const bf16x8*)((const char*)lB[z] + r * 128 +
                                    ((c ^ (r & 7)) << 4));
        }
#pragma unroll
        for (int m = 0; m < 4; ++m)
#pragma unroll
          for (int n = 0; n < 2; ++n)
            acc[z][m][n] = mfma16(af[m], bfr[n], acc[z][m][n]);
      }
    }
    __syncthreads();
  }
  // epilogue
#pragma unroll
  for (int z = 0; z < 3; ++z) {
    bf16_t* outb = (z == 0) ? qo : ((z == 1) ? ko : vt);
    const float qs = (z == 0) ? 0.125f : 1.0f;  // fold 1/sqrt(64) into Q
#pragma unroll
    for (int m = 0; m < 4; ++m) {
#pragma unroll
      for (int n = 0; n < 2; ++n) {
        const int gr = row0 + wr * 64 + m * 16 + ((lane >> 4) << 2);
        const int gc = col0 + wc * 32 + n * 16 + (lane & 15);
        const int b = gr >> 11, t = gr & (T_ - 1);
        const int h = gc >> 6, d = gc & 63;
        if (z < 2) {
#pragma unroll
          for (int j = 0; j < 4; ++j)
            outb[(((size_t)(b * H_ + h)) * T_ + (t + j)) * D_ + d] =
                (bf16_t)(acc[z][m][n][j] * qs);
        } else {
          bf16x4 pk = {(bf16_t)acc[z][m][n][0], (bf16_t)acc[z][m][n][1],
                       (bf16_t)acc[z][m][n][2], (bf16_t)acc[z][m][n][3]};
          *(bf16x4*)(outb + (((size_t)(b * H_ + h)) * D_ + d) * T_ + t) = pk;
        }
      }
    }
  }
}

// ------------------------------------------------------------ GEMM main loop
// (used by gemm_proj) C = A(MxK) * W(NxK)^T, 128x128 tile, 256 threads.
__device__ __forceinline__ void gemm_mainloop(const bf16_t* __restrict__ A,
                                              const bf16_t* __restrict__ W,
                                              bf16_t* lA, bf16_t* lB, int row0,
                                              int col0, f32x4 (&acc)[4][4]) {
  const int tid = threadIdx.x;
  const int wave = tid >> 6, lane = tid & 63;
  const int wr = wave >> 1, wc = wave & 1;
  for (int k0 = 0; k0 < C_; k0 += 64) {
#pragma unroll
    for (int it = 0; it < 4; ++it) {
      const int off = (it * 4 + wave) * 1024;  // bytes, wave-uniform
      const int lin = off + lane * 16;
      const int r = lin >> 7;
      const int c = ((lin >> 4) & 7) ^ (r & 7);
      GLDS(A + (size_t)(row0 + r) * C_ + k0 + c * 8, lA + (off >> 1));
      GLDS(W + (size_t)(col0 + r) * C_ + k0 + c * 8, lB + (off >> 1));
    }
    __syncthreads();
#pragma unroll
    for (int s = 0; s < 2; ++s) {
      bf16x8 af[4], bfr[4];
#pragma unroll
      for (int m = 0; m < 4; ++m) {
        const int r = wr * 64 + m * 16 + (lane & 15);
        const int c = s * 4 + (lane >> 4);
        af[m] = *(const bf16x8*)((const char*)lA + r * 128 +
                                 ((c ^ (r & 7)) << 4));
      }
#pragma unroll
      for (int n = 0; n < 4; ++n) {
        const int r = wc * 64 + n * 16 + (lane & 15);
        const int c = s * 4 + (lane >> 4);
        bfr[n] = *(const bf16x8*)((const char*)lB + r * 128 +
                                  ((c ^ (r & 7)) << 4));
      }
#pragma unroll
      for (int m = 0; m < 4; ++m)
#pragma unroll
        for (int n = 0; n < 4; ++n) acc[m][n] = mfma16(af[m], bfr[n], acc[m][n]);
    }
    __syncthreads();
  }
}

// Output projection + bias, f32 out.
__global__ __launch_bounds__(256) void gemm_proj(const bf16_t* __restrict__ att,
                                                 const bf16_t* __restrict__ wp,
                                                 const float* __restrict__ bias,
                                                 float* __restrict__ out) {
  __shared__ bf16_t lA[128 * 64];
  __shared__ bf16_t lB[128 * 64];
  const int row0 = blockIdx.y * 128, col0 = blockIdx.x * 128;
  f32x4 acc[4][4] = {};
  gemm_mainloop(att, wp, lA, lB, row0, col0, acc);
  const int lane = threadIdx.x & 63, wave = threadIdx.x >> 6;
  const int wr = wave >> 1, wc = wave & 1;
#pragma unroll
  for (int m = 0; m < 4; ++m) {
#pragma unroll
    for (int n = 0; n < 4; ++n) {
      const int gr = row0 + wr * 64 + m * 16 + ((lane >> 4) << 2);
      const int gc = col0 + wc * 64 + n * 16 + (lane & 15);
      const float bv = bias[gc];
#pragma unroll
      for (int j = 0; j < 4; ++j)
        out[(size_t)(gr + j) * C_ + gc] = acc[m][n][j] + bv;
    }
  }
}

// --------------------------------------------------------- flash attention v8
// 8 waves x 16 q-rows = 128-row q-tile per block; paired (x, 15-x) -> 512
// uniform blocks x 34 iters. Swapped QK^T: lane holds 16 scores of ONE q-row
// (q=lane&15, kv = nf*16+g*4+j); 15 local fmax + 2 shfl hops; __expf path.
__global__ __launch_bounds__(512, 4) void attn_fwd(
    const bf16_t* __restrict__ Q, const bf16_t* __restrict__ K,
    const bf16_t* __restrict__ V, bf16_t* __restrict__ AO) {
  __shared__ bf16_t lK[2][64 * 64];
  __shared__ bf16_t lV[2][64 * 64];   // V^T tile: [d][s]
  __shared__ bf16_t lP[8][16 * 64];   // per-wave P re-layout buffer
  const int tid = threadIdx.x, wave = tid >> 6, lane = tid & 63;
  const int g = lane >> 4;            // 16-lane group id
  const int bh = blockIdx.y;
  const size_t baseK = (size_t)bh * T_ * D_;
  const size_t baseV = (size_t)bh * D_ * T_;
  const int bb = bh >> 4, hh = bh & 15;

  for (int half = 0; half < 2; ++half) {
    const int qt = half ? (15 - blockIdx.x) : blockIdx.x;
    const int twv = qt * 128 + wave * 16;  // this wave's 16 q-rows
    const int ntiles = 2 * qt + 2;
    __syncthreads();  // protect LDS buffers from previous half's readers
    // prologue: stage tile 0 into buf 0 (each wave stages 1KB per buffer)
    {
      const int off = wave * 1024;
      const int lin = off + lane * 16;
      const int r = lin >> 7;
      const int c = ((lin >> 4) & 7) ^ (r & 7);
      GLDS(K + baseK + (size_t)r * D_ + c * 8, &lK[0][off >> 1]);
      GLDS(V + baseV + (size_t)r * T_ + c * 8, &lV[0][off >> 1]);
    }
    // Q fragments (operand layout: row=lane&15, k=g*8+e); Q pre-scaled 0.125.
    bf16x8 qf[2];
#pragma unroll
    for (int s = 0; s < 2; ++s)
      qf[s] = *(const bf16x8*)(Q + baseK +
                               (size_t)(twv + (lane & 15)) * D_ + s * 32 +
                               (g << 3));
    float mrun = -1e30f, lrun = 0.f;
    f32x4 o[4] = {};
    int cur = 0;
    for (int it = 0; it < ntiles; ++it) {
      __syncthreads();  // staging into `cur` complete; readers of cur^1 done
      if (it + 1 < ntiles) {
        const int s0n = (it + 1) * 64;
        const int nb = cur ^ 1;
        const int off = wave * 1024;
        const int lin = off + lane * 16;
        const int r = lin >> 7;
        const int c = ((lin >> 4) & 7) ^ (r & 7);
        GLDS(K + baseK + (size_t)(s0n + r) * D_ + c * 8, &lK[nb][off >> 1]);
        GLDS(V + baseV + (size_t)r * T_ + s0n + c * 8, &lV[nb][off >> 1]);
      }
      const int s0 = it * 64;
      // S^T = K Q^T: rows kv (4 nf-frags), cols q (this wave's 16 rows)
      f32x4 sc[4];
#pragma unroll
      for (int nf = 0; nf < 4; ++nf) sc[nf] = (f32x4){};
      __builtin_amdgcn_s_setprio(1);
#pragma unroll
      for (int s = 0; s < 2; ++s) {
#pragma unroll
        for (int nf = 0; nf < 4; ++nf) {
          const int r = nf * 16 + (lane & 15);
          const int c = s * 4 + g;
          bf16x8 kf = *(const bf16x8*)((const char*)lK[cur] + r * 128 +
                                       ((c ^ (r & 7)) << 4));
          sc[nf] = mfma16(kf, qf[s], sc[nf]);  // swapped operands
        }
      }
      __builtin_amdgcn_s_setprio(0);
      // causal mask (only the last two tiles touch the diagonal)
      if (it >= 2 * qt) {
        const int t = twv + (lane & 15);
#pragma unroll
        for (int nf = 0; nf < 4; ++nf)
#pragma unroll
          for (int j = 0; j < 4; ++j) {
            const int s = s0 + nf * 16 + g * 4 + j;
            if (s > t) sc[nf][j] = -1e30f;
          }
      }
      // online softmax; whole q-row lane-local + 2 hops
      float pmax = sc[0][0];
#pragma unroll
      for (int nf = 0; nf < 4; ++nf)
#pragma unroll
        for (int j = 0; j < 4; ++j) pmax = fmaxf(pmax, sc[nf][j]);
      pmax = fmaxf(pmax, __shfl_xor(pmax, 16));
      pmax = fmaxf(pmax, __shfl_xor(pmax, 32));
      const float mn = fmaxf(mrun, pmax);
      const float scl = __expf(mrun - mn);
      mrun = mn;
      float ps = 0.f;
      bf16x4 pk[4];
#pragma unroll
      for (int nf = 0; nf < 4; ++nf)
#pragma unroll
        for (int j = 0; j < 4; ++j) {
          const float p = __expf(sc[nf][j] - mn);
          ps += p;
          pk[nf][j] = (bf16_t)p;
        }
      ps += __shfl_xor(ps, 16);
      ps += __shfl_xor(ps, 32);
      lrun = lrun * scl + ps;
      // broadcast scl from q-col holders to O-row holders, rescale O
      float sb[4];
#pragma unroll
      for (int j = 0; j < 4; ++j)
        sb[j] = __shfl(scl, (lane & 48) | ((g << 2) + j));
#pragma unroll
      for (int df = 0; df < 4; ++df)
#pragma unroll
        for (int j = 0; j < 4; ++j) o[df][j] *= sb[j];
      // P -> LDS: row q (lane&15), packed bf16x4 per nf (XOR-16B involution)
      {
        const int r = lane & 15;
#pragma unroll
        for (int nf = 0; nf < 4; ++nf)
          *(bf16x4*)((char*)lP[wave] + r * 128 +
                     ((((2 * nf + (g >> 1)) ^ (r & 7)) << 4) |
                      ((g & 1) << 3))) = pk[nf];
      }
      // O += P V  (A = P rows q, B = V^T rows d, K = kv)
      __builtin_amdgcn_s_setprio(1);
#pragma unroll
      for (int s2 = 0; s2 < 2; ++s2) {
        const int cp = s2 * 4 + g;
        const int rp = lane & 15;
        bf16x8 pf = *(const bf16x8*)((const char*)lP[wave] + rp * 128 +
                                     ((cp ^ (rp & 7)) << 4));
#pragma unroll
        for (int df = 0; df < 4; ++df) {
          const int rv = df * 16 + (lane & 15);
          bf16x8 vf = *(const bf16x8*)((const char*)lV[cur] + rv * 128 +
                                       ((cp ^ (rv & 7)) << 4));
          o[df] = mfma16(pf, vf, o[df]);
        }
      }
      __builtin_amdgcn_s_setprio(0);
      cur ^= 1;
    }
    // epilogue: normalized O -> [B][T][C] bf16 (broadcast 1/l to row holders)
    {
      const float inv = 1.0f / lrun;
      float ib[4];
#pragma unroll
      for (int j = 0; j < 4; ++j)
        ib[j] = __shfl(inv, (lane & 48) | ((g << 2) + j));
#pragma unroll
      for (int j = 0; j < 4; ++j) {
        const int t = twv + (g << 2) + j;
#pragma unroll
        for (int df = 0; df < 4; ++df) {
          const int cc = hh * 64 + df * 16 + (lane & 15);
          AO[((size_t)(bb * T_ + t)) * C_ + cc] = (bf16_t)(o[df][j] * ib[j]);
        }
      }
    }
  }
}

// ---------------------------------------------------------------- launcher
extern "C" void kernel_launch(void* const* d_in, const int* in_sizes, int n_in,
                              void* d_out, int out_size, void* d_ws,
                              size_t ws_size, hipStream_t stream) {
  const float* x = (const float*)d_in[0];
  const float* Wk = (const float*)d_in[1];
  const float* Wq = (const float*)d_in[2];
  const float* Wv = (const float*)d_in[3];
  const float* Wp = (const float*)d_in[4];
  const float* bp = (const float*)d_in[5];
  char* ws = (char*)d_ws;
  // workspace layout (72 MiB):
  bf16_t* xb = (bf16_t*)ws;                          // 16 MiB (reused as att)
  bf16_t* wqb = (bf16_t*)(ws + (16u << 20));         // 2 MiB
  bf16_t* wkb = (bf16_t*)(ws + (18u << 20));         // 2 MiB
  bf16_t* wvb = (bf16_t*)(ws + (20u << 20));         // 2 MiB
  bf16_t* wpb = (bf16_t*)(ws + (22u << 20));         // 2 MiB
  bf16_t* q = (bf16_t*)(ws + (24u << 20));           // 16 MiB [B][H][T][D]
  bf16_t* k = (bf16_t*)(ws + (40u << 20));           // 16 MiB [B][H][T][D]
  bf16_t* vt = (bf16_t*)(ws + (56u << 20));          // 16 MiB [B][H][D][T]
  bf16_t* att = xb;  // x no longer needed once QKV GEMMs are done

  cvt_all<<<12288, 256, 0, stream>>>(x, Wq, Wk, Wv, Wp, xb, wqb, wkb, wvb, wpb);
  gemm_qkv<<<512, 512, 0, stream>>>(xb, wqb, wkb, wvb, q, k, vt);
  attn_fwd<<<dim3(8, 64), 512, 0, stream>>>(q, k, vt, att);
  gemm_proj<<<dim3(8, 64), 256, 0, stream>>>(att, wpb, bp, (float*)d_out);
}

// Round 10
// 176.831 us; speedup vs baseline: 1.2775x; 1.0169x over previous
//
#include <hip/hip_runtime.h>

typedef __bf16 bf16_t;
typedef bf16_t bf16x4 __attribute__((ext_vector_type(4)));
typedef bf16_t bf16x8 __attribute__((ext_vector_type(8)));
typedef float f32x4 __attribute__((ext_vector_type(4)));

#define B_ 4
#define T_ 2048
#define C_ 1024
#define H_ 16
#define D_ 64

// global -> LDS direct copy, 16B per lane; LDS dest must be wave-uniform base
// (HW adds lane*16). Source is per-lane (pre-swizzled to realize LDS swizzle).
#define GLDS(g, l)                                                          \
  __builtin_amdgcn_global_load_lds(                                         \
      (const __attribute__((address_space(1))) void*)(g),                   \
      (__attribute__((address_space(3))) void*)(l), 16, 0, 0)

static __device__ __forceinline__ f32x4 mfma16(bf16x8 a, bf16x8 b, f32x4 c) {
  return __builtin_amdgcn_mfma_f32_16x16x32_bf16(a, b, c, 0, 0, 0);
}

// bare 2^x — exactly one v_exp_f32 (libm exp2f has a slow guard path; __expf
// adds a v_mul by log2e). Input domain here is always <= 0 or ~-1e30 (masked),
// both handled natively (v_exp(-huge) -> 0).
static __device__ __forceinline__ float exp2_hw(float x) {
  float r;
  asm("v_exp_f32 %0, %1" : "=v"(r) : "v"(x));
  return r;
}

// ---------------------------------------------------------------- convert
// One launch converts x + the 4 weight matrices.
__global__ void cvt_all(const float* __restrict__ x, const float* __restrict__ wq,
                        const float* __restrict__ wk, const float* __restrict__ wv,
                        const float* __restrict__ wp, bf16_t* __restrict__ xb,
                        bf16_t* __restrict__ wqb, bf16_t* __restrict__ wkb,
                        bf16_t* __restrict__ wvb, bf16_t* __restrict__ wpb) {
  int i = blockIdx.x * blockDim.x + threadIdx.x;  // float4 index
  const float* src;
  bf16_t* dst;
  int off;
  if (i < 2097152) {
    src = x; dst = xb; off = i;
  } else {
    int r = i - 2097152;
    int region = r >> 18;  // 262144 float4 per weight
    off = r & 262143;
    if (region == 0) { src = wq; dst = wqb; }
    else if (region == 1) { src = wk; dst = wkb; }
    else if (region == 2) { src = wv; dst = wvb; }
    else { src = wp; dst = wpb; }
  }
  float4 v = ((const float4*)src)[off];
  bf16x4 o = {(bf16_t)v.x, (bf16_t)v.y, (bf16_t)v.z, (bf16_t)v.w};
  ((bf16x4*)dst)[off] = o;
}

// --------------------------------------------- fused QKV GEMM (z inside)
// One block computes the SAME 128x128 output tile for Q, K and V:
// A-tile staged once per k-step, ds_reads shared across 3 B-operands.
// 512 threads = 8 waves (2 row x 4 col), wave tile 64x32 per z.
// XCD-chunked swizzle for A-panel L2 reuse.
// z=0: Q (pre-scaled log2e/8 for exp2-domain attention) -> [B][H][T][D];
// z=1: K -> [B][H][T][D]; z=2: V -> transposed [B][H][D][T].
__global__ __launch_bounds__(512) void gemm_qkv(
    const bf16_t* __restrict__ xb, const bf16_t* __restrict__ wq,
    const bf16_t* __restrict__ wk, const bf16_t* __restrict__ wv,
    bf16_t* __restrict__ qo, bf16_t* __restrict__ ko, bf16_t* __restrict__ vt) {
  __shared__ bf16_t lA[128 * 64];
  __shared__ bf16_t lB[3][128 * 64];
  const int tid = threadIdx.x, wave = tid >> 6, lane = tid & 63;
  const int g = lane >> 4;
  const int bid = blockIdx.x;
  const int swz = ((bid & 7) << 6) | (bid >> 3);  // 64-block chunk per XCD
  const int col0 = (swz & 7) * 128, row0 = (swz >> 3) * 128;
  const int wr = wave >> 2, wc = wave & 3;  // 2 x 4 wave grid
  f32x4 acc[3][4][2] = {};
  for (int k0 = 0; k0 < C_; k0 += 64) {
#pragma unroll
    for (int i = 0; i < 2; ++i) {
      const int off = (i * 8 + wave) * 1024;  // bytes, wave-uniform
      const int lin = off + lane * 16;
      const int r = lin >> 7;
      const int c = ((lin >> 4) & 7) ^ (r & 7);
      GLDS(xb + (size_t)(row0 + r) * C_ + k0 + c * 8, lA + (off >> 1));
      GLDS(wq + (size_t)(col0 + r) * C_ + k0 + c * 8, &lB[0][off >> 1]);
      GLDS(wk + (size_t)(col0 + r) * C_ + k0 + c * 8, &lB[1][off >> 1]);
      GLDS(wv + (size_t)(col0 + r) * C_ + k0 + c * 8, &lB[2][off >> 1]);
    }
    __syncthreads();
#pragma unroll
    for (int s = 0; s < 2; ++s) {
      const int c = s * 4 + g;
      bf16x8 af[4];
#pragma unroll
      for (int m = 0; m < 4; ++m) {
        const int r = wr * 64 + m * 16 + (lane & 15);
        af[m] = *(const bf16x8*)((const char*)lA + r * 128 +
                                 ((c ^ (r & 7)) << 4));
      }
#pragma unroll
      for (int z = 0; z < 3; ++z) {
        bf16x8 bfr[2];
#pragma unroll
        for (int n = 0; n < 2; ++n) {
          const int r = wc * 32 + n * 16 + (lane & 15);
          bfr[n] = *(const bf16x8*)((const char*)lB[z] + r * 128 +
                                    ((c ^ (r & 7)) << 4));
        }
#pragma unroll
        for (int m = 0; m < 4; ++m)
#pragma unroll
          for (int n = 0; n < 2; ++n)
            acc[z][m][n] = mfma16(af[m], bfr[n], acc[z][m][n]);
      }
    }
    __syncthreads();
  }
  // epilogue
#pragma unroll
  for (int z = 0; z < 3; ++z) {
    bf16_t* outb = (z == 0) ? qo : ((z == 1) ? ko : vt);
    // fold 1/sqrt(64) * log2(e) into Q so attention softmax is pure v_exp
    const float qs = (z == 0) ? 0.125f * 1.4426950408889634f : 1.0f;
#pragma unroll
    for (int m = 0; m < 4; ++m) {
#pragma unroll
      for (int n = 0; n < 2; ++n) {
        const int gr = row0 + wr * 64 + m * 16 + ((lane >> 4) << 2);
        const int gc = col0 + wc * 32 + n * 16 + (lane & 15);
        const int b = gr >> 11, t = gr & (T_ - 1);
        const int h = gc >> 6, d = gc & 63;
        if (z < 2) {
#pragma unroll
          for (int j = 0; j < 4; ++j)
            outb[(((size_t)(b * H_ + h)) * T_ + (t + j)) * D_ + d] =
                (bf16_t)(acc[z][m][n][j] * qs);
        } else {
          bf16x4 pk = {(bf16_t)acc[z][m][n][0], (bf16_t)acc[z][m][n][1],
                       (bf16_t)acc[z][m][n][2], (bf16_t)acc[z][m][n][3]};
          *(bf16x4*)(outb + (((size_t)(b * H_ + h)) * D_ + d) * T_ + t) = pk;
        }
      }
    }
  }
}

// ------------------------------------------------------------ GEMM main loop
// (used by gemm_proj) C = A(MxK) * W(NxK)^T, 128x128 tile, 256 threads.
__device__ __forceinline__ void gemm_mainloop(const bf16_t* __restrict__ A,
                                              const bf16_t* __restrict__ W,
                                              bf16_t* lA, bf16_t* lB, int row0,
                                              int col0, f32x4 (&acc)[4][4]) {
  const int tid = threadIdx.x;
  const int wave = tid >> 6, lane = tid & 63;
  const int wr = wave >> 1, wc = wave & 1;
  for (int k0 = 0; k0 < C_; k0 += 64) {
#pragma unroll
    for (int it = 0; it < 4; ++it) {
      const int off = (it * 4 + wave) * 1024;  // bytes, wave-uniform
      const int lin = off + lane * 16;
      const int r = lin >> 7;
      const int c = ((lin >> 4) & 7) ^ (r & 7);
      GLDS(A + (size_t)(row0 + r) * C_ + k0 + c * 8, lA + (off >> 1));
      GLDS(W + (size_t)(col0 + r) * C_ + k0 + c * 8, lB + (off >> 1));
    }
    __syncthreads();
#pragma unroll
    for (int s = 0; s < 2; ++s) {
      bf16x8 af[4], bfr[4];
#pragma unroll
      for (int m = 0; m < 4; ++m) {
        const int r = wr * 64 + m * 16 + (lane & 15);
        const int c = s * 4 + (lane >> 4);
        af[m] = *(const bf16x8*)((const char*)lA + r * 128 +
                                 ((c ^ (r & 7)) << 4));
      }
#pragma unroll
      for (int n = 0; n < 4; ++n) {
        const int r = wc * 64 + n * 16 + (lane & 15);
        const int c = s * 4 + (lane >> 4);
        bfr[n] = *(const bf16x8*)((const char*)lB + r * 128 +
                                  ((c ^ (r & 7)) << 4));
      }
#pragma unroll
      for (int m = 0; m < 4; ++m)
#pragma unroll
        for (int n = 0; n < 4; ++n) acc[m][n] = mfma16(af[m], bfr[n], acc[m][n]);
    }
    __syncthreads();
  }
}

// Output projection + bias, f32 out.
__global__ __launch_bounds__(256) void gemm_proj(const bf16_t* __restrict__ att,
                                                 const bf16_t* __restrict__ wp,
                                                 const float* __restrict__ bias,
                                                 float* __restrict__ out) {
  __shared__ bf16_t lA[128 * 64];
  __shared__ bf16_t lB[128 * 64];
  const int row0 = blockIdx.y * 128, col0 = blockIdx.x * 128;
  f32x4 acc[4][4] = {};
  gemm_mainloop(att, wp, lA, lB, row0, col0, acc);
  const int lane = threadIdx.x & 63, wave = threadIdx.x >> 6;
  const int wr = wave >> 1, wc = wave & 1;
#pragma unroll
  for (int m = 0; m < 4; ++m) {
#pragma unroll
    for (int n = 0; n < 4; ++n) {
      const int gr = row0 + wr * 64 + m * 16 + ((lane >> 4) << 2);
      const int gc = col0 + wc * 64 + n * 16 + (lane & 15);
      const float bv = bias[gc];
#pragma unroll
      for (int j = 0; j < 4; ++j)
        out[(size_t)(gr + j) * C_ + gc] = acc[m][n][j] + bv;
    }
  }
}

// -------------------------------------------------------- flash attention v10
// 8 waves x 16 q-rows = 128-row q-tile per block; paired (x, 15-x) -> 512
// uniform blocks x 34 iters. Swapped QK^T: lane holds 16 scores of ONE q-row
// (q=lane&15, kv = nf*16+g*4+j). exp2 domain (Q pre-scaled log2e/8), bare
// v_exp_f32 via asm. Rescale (broadcast+o-mul) only when the running max
// actually grows (__any guard — tiny branch, no body duplication).
__global__ __launch_bounds__(512, 4) void attn_fwd(
    const bf16_t* __restrict__ Q, const bf16_t* __restrict__ K,
    const bf16_t* __restrict__ V, bf16_t* __restrict__ AO) {
  __shared__ bf16_t lK[2][64 * 64];
  __shared__ bf16_t lV[2][64 * 64];   // V^T tile: [d][s]
  __shared__ bf16_t lP[8][16 * 64];   // per-wave P re-layout buffer
  const int tid = threadIdx.x, wave = tid >> 6, lane = tid & 63;
  const int g = lane >> 4;            // 16-lane group id
  const int bh = blockIdx.y;
  const size_t baseK = (size_t)bh * T_ * D_;
  const size_t baseV = (size_t)bh * D_ * T_;
  const int bb = bh >> 4, hh = bh & 15;

  for (int half = 0; half < 2; ++half) {
    const int qt = half ? (15 - blockIdx.x) : blockIdx.x;
    const int twv = qt * 128 + wave * 16;  // this wave's 16 q-rows
    const int ntiles = 2 * qt + 2;
    __syncthreads();  // protect LDS buffers from previous half's readers
    // prologue: stage tile 0 into buf 0 (each wave stages 1KB per buffer)
    {
      const int off = wave * 1024;
      const int lin = off + lane * 16;
      const int r = lin >> 7;
      const int c = ((lin >> 4) & 7) ^ (r & 7);
      GLDS(K + baseK + (size_t)r * D_ + c * 8, &lK[0][off >> 1]);
      GLDS(V + baseV + (size_t)r * T_ + c * 8, &lV[0][off >> 1]);
    }
    // Q fragments (operand layout: row=lane&15, k=g*8+e); Q pre-scaled.
    bf16x8 qf[2];
#pragma unroll
    for (int s = 0; s < 2; ++s)
      qf[s] = *(const bf16x8*)(Q + baseK +
                               (size_t)(twv + (lane & 15)) * D_ + s * 32 +
                               (g << 3));
    float mrun = -1e30f, lrun = 0.f;
    f32x4 o[4] = {};
    int cur = 0;
    for (int it = 0; it < ntiles; ++it) {
      __syncthreads();  // staging into `cur` complete; readers of cur^1 done
      if (it + 1 < ntiles) {
        const int s0n = (it + 1) * 64;
        const int nb = cur ^ 1;
        const int off = wave * 1024;
        const int lin = off + lane * 16;
        const int r = lin >> 7;
        const int c = ((lin >> 4) & 7) ^ (r & 7);
        GLDS(K + baseK + (size_t)(s0n + r) * D_ + c * 8, &lK[nb][off >> 1]);
        GLDS(V + baseV + (size_t)r * T_ + s0n + c * 8, &lV[nb][off >> 1]);
      }
      const int s0 = it * 64;
      // S^T = K Q^T: rows kv (4 nf-frags), cols q (this wave's 16 rows)
      f32x4 sc[4];
#pragma unroll
      for (int nf = 0; nf < 4; ++nf) sc[nf] = (f32x4){};
      __builtin_amdgcn_s_setprio(1);
#pragma unroll
      for (int s = 0; s < 2; ++s) {
#pragma unroll
        for (int nf = 0; nf < 4; ++nf) {
          const int r = nf * 16 + (lane & 15);
          const int c = s * 4 + g;
          bf16x8 kf = *(const bf16x8*)((const char*)lK[cur] + r * 128 +
                                       ((c ^ (r & 7)) << 4));
          sc[nf] = mfma16(kf, qf[s], sc[nf]);  // swapped operands
        }
      }
      __builtin_amdgcn_s_setprio(0);
      // causal mask (only the last two tiles touch the diagonal)
      if (it >= 2 * qt) {
        const int t = twv + (lane & 15);
#pragma unroll
        for (int nf = 0; nf < 4; ++nf)
#pragma unroll
          for (int j = 0; j < 4; ++j) {
            const int s = s0 + nf * 16 + g * 4 + j;
            if (s > t) sc[nf][j] = -1e30f;
          }
      }
      // online softmax (exp2 domain); whole q-row lane-local + 2 hops
      float t0 = fmaxf(fmaxf(sc[0][0], sc[0][1]), fmaxf(sc[0][2], sc[0][3]));
      float t1 = fmaxf(fmaxf(sc[1][0], sc[1][1]), fmaxf(sc[1][2], sc[1][3]));
      float t2 = fmaxf(fmaxf(sc[2][0], sc[2][1]), fmaxf(sc[2][2], sc[2][3]));
      float t3 = fmaxf(fmaxf(sc[3][0], sc[3][1]), fmaxf(sc[3][2], sc[3][3]));
      float pmax = fmaxf(fmaxf(t0, t1), fmaxf(t2, t3));
      pmax = fmaxf(pmax, __shfl_xor(pmax, 16));
      pmax = fmaxf(pmax, __shfl_xor(pmax, 32));
      if (__any(pmax > mrun)) {  // running max grew somewhere: rescale
        const float mn = fmaxf(mrun, pmax);
        const float scl = exp2_hw(mrun - mn);
        mrun = mn;
        lrun *= scl;
        float sb[4];
#pragma unroll
        for (int j = 0; j < 4; ++j)
          sb[j] = __shfl(scl, (lane & 48) | ((g << 2) + j));
#pragma unroll
        for (int df = 0; df < 4; ++df)
#pragma unroll
          for (int j = 0; j < 4; ++j) o[df][j] *= sb[j];
      }
      float ps = 0.f;
      bf16x4 pk[4];
#pragma unroll
      for (int nf = 0; nf < 4; ++nf)
#pragma unroll
        for (int j = 0; j < 4; ++j) {
          const float p = exp2_hw(sc[nf][j] - mrun);
          ps += p;
          pk[nf][j] = (bf16_t)p;
        }
      ps += __shfl_xor(ps, 16);
      ps += __shfl_xor(ps, 32);
      lrun += ps;
      // P -> LDS: row q (lane&15), packed bf16x4 per nf (XOR-16B involution)
      {
        const int r = lane & 15;
#pragma unroll
        for (int nf = 0; nf < 4; ++nf)
          *(bf16x4*)((char*)lP[wave] + r * 128 +
                     ((((2 * nf + (g >> 1)) ^ (r & 7)) << 4) |
                      ((g & 1) << 3))) = pk[nf];
      }
      // O += P V  (A = P rows q, B = V^T rows d, K = kv)
      __builtin_amdgcn_s_setprio(1);
#pragma unroll
      for (int s2 = 0; s2 < 2; ++s2) {
        const int cp = s2 * 4 + g;
        const int rp = lane & 15;
        bf16x8 pf = *(const bf16x8*)((const char*)lP[wave] + rp * 128 +
                                     ((cp ^ (rp & 7)) << 4));
#pragma unroll
        for (int df = 0; df < 4; ++df) {
          const int rv = df * 16 + (lane & 15);
          bf16x8 vf = *(const bf16x8*)((const char*)lV[cur] + rv * 128 +
                                       ((cp ^ (rv & 7)) << 4));
          o[df] = mfma16(pf, vf, o[df]);
        }
      }
      __builtin_amdgcn_s_setprio(0);
      cur ^= 1;
    }
    // epilogue: normalized O -> [B][T][C] bf16 (broadcast 1/l to row holders)
    {
      const float inv = 1.0f / lrun;
      float ib[4];
#pragma unroll
      for (int j = 0; j < 4; ++j)
        ib[j] = __shfl(inv, (lane & 48) | ((g << 2) + j));
#pragma unroll
      for (int j = 0; j < 4; ++j) {
        const int t = twv + (g << 2) + j;
#pragma unroll
        for (int df = 0; df < 4; ++df) {
          const int cc = hh * 64 + df * 16 + (lane & 15);
          AO[((size_t)(bb * T_ + t)) * C_ + cc] = (bf16_t)(o[df][j] * ib[j]);
        }
      }
    }
  }
}

// ---------------------------------------------------------------- launcher
extern "C" void kernel_launch(void* const* d_in, const int* in_sizes, int n_in,
                              void* d_out, int out_size, void* d_ws,
                              size_t ws_size, hipStream_t stream) {
  const float* x = (const float*)d_in[0];
  const float* Wk = (const float*)d_in[1];
  const float* Wq = (const float*)d_in[2];
  const float* Wv = (const float*)d_in[3];
  const float* Wp = (const float*)d_in[4];
  const float* bp = (const float*)d_in[5];
  char* ws = (char*)d_ws;
  // workspace layout (72 MiB):
  bf16_t* xb = (bf16_t*)ws;                          // 16 MiB (reused as att)
  bf16_t* wqb = (bf16_t*)(ws + (16u << 20));         // 2 MiB
  bf16_t* wkb = (bf16_t*)(ws + (18u << 20));         // 2 MiB
  bf16_t* wvb = (bf16_t*)(ws + (20u << 20));         // 2 MiB
  bf16_t* wpb = (bf16_t*)(ws + (22u << 20));         // 2 MiB
  bf16_t* q = (bf16_t*)(ws + (24u << 20));           // 16 MiB [B][H][T][D]
  bf16_t* k = (bf16_t*)(ws + (40u << 20));           // 16 MiB [B][H][T][D]
  bf16_t* vt = (bf16_t*)(ws + (56u << 20));          // 16 MiB [B][H][D][T]
  bf16_t* att = xb;  // x no longer needed once QKV GEMMs are done

  cvt_all<<<12288, 256, 0, stream>>>(x, Wq, Wk, Wv, Wp, xb, wqb, wkb, wvb, wpb);
  gemm_qkv<<<512, 512, 0, stream>>>(xb, wqb, wkb, wvb, q, k, vt);
  attn_fwd<<<dim3(8, 64), 512, 0, stream>>>(q, k, vt, att);
  gemm_proj<<<dim3(8, 64), 256, 0, stream>>>(att, wpb, bp, (float*)d_out);
}